// Round 17
// baseline (276.692 us; speedup 1.0000x reference)
//
#include <hip/hip_runtime.h>
#include <math.h>

// BS=128, L=256, D=512, H=2, DK=256.
// Conv branches dead (gather idx < 256). ALL GEMMs 1-pass bf16 MFMA,
// __syncthreads-only. Compositions: Wa = Wfq@Wq_h, Wb = Wfk@Wk_h (both
// gate-shielded). Mega-kernel gemm_gkg: phase A dual-B (cap@Wa, cap@Wb) ->
// G kept in LDS only; phase B G(LDS)@Wfg2^T; phase C cap@Wk^T (fp32 K);
// epilogue fused kg*qg score reduce. G never hits HBM. qg computes its own
// G at gathered rows. V GEMM removed via x=(p@cap)@Wv^T+bv.

typedef short bf16x8 __attribute__((ext_vector_type(8)));
typedef float f32x4 __attribute__((ext_vector_type(4)));
typedef short short4v __attribute__((ext_vector_type(4)));

__device__ __forceinline__ short f2bf(float x) {
    union { float f; unsigned u; } c; c.f = x;
    unsigned r = c.u + 0x7FFFu + ((c.u >> 16) & 1u);
    return (short)(r >> 16);
}
__device__ __forceinline__ float bf2f(short h) {
    union { float f; unsigned u; } c; c.u = ((unsigned)(unsigned short)h) << 16;
    return c.f;
}
__device__ __forceinline__ void glds16(const void* g, void* l) {
    __builtin_amdgcn_global_load_lds(
        (const __attribute__((address_space(1))) void*)g,
        (__attribute__((address_space(3))) void*)l, 16, 0, 0);
}

// ---------------- cast fp32 -> bf16 ----------------
struct CastArgs {
    const float* src[3];
    short* dst[3];
    int n4[3];
};
__global__ __launch_bounds__(256) void cast_multi(CastArgs a)
{
    const int j = blockIdx.y;
    const float4* s = (const float4*)a.src[j];
    short* d = a.dst[j];
    const int n4 = a.n4[j];
    for (int i = blockIdx.x * 256 + threadIdx.x; i < n4; i += gridDim.x * 256) {
        float4 x = s[i];
        short4v h;
        h.x = f2bf(x.x); h.y = f2bf(x.y); h.z = f2bf(x.z); h.w = f2bf(x.w);
        *(short4v*)&d[i * 4] = h;
    }
}

// ---------------- composed weights: W∘ = F @ W_h (bf16), b∘ = F@b_h + bf ----
__global__ __launch_bounds__(256)
void compose2(const float* __restrict__ Wq, const float* __restrict__ bq,
              const float* __restrict__ Wfq, const float* __restrict__ bfq,
              const float* __restrict__ Wk, const float* __restrict__ bk,
              const float* __restrict__ Wfk, const float* __restrict__ bfk,
              short* __restrict__ WaB, float* __restrict__ ba,
              short* __restrict__ WbB, float* __restrict__ bb)
{
    __shared__ float fq[256];
    __shared__ float redc[256];
    const int op = blockIdx.x;          // 0..511: h = op>>8, o = op&255
    const int h = op >> 8, o = op & 255;
    const int t = threadIdx.x;
    const bool second = (blockIdx.y == 1);
    const float* W  = second ? Wk  : Wq;
    const float* bv = second ? bk  : bq;
    const float* F  = second ? Wfk : Wfq;
    const float* bf = second ? bfk : bfq;
    short* WB   = second ? WbB : WaB;
    float* bout = second ? bb  : ba;

    fq[t] = F[o * 256 + t];
    redc[t] = fq[t] * bv[h * 256 + t];
    __syncthreads();
    for (int s = 128; s > 0; s >>= 1) {
        if (t < s) redc[t] += redc[t + s];
        __syncthreads();
    }
    if (t == 0) bout[op] = redc[0] + bf[o];
    float s0 = 0.f, s1 = 0.f;
    for (int d = 0; d < 256; ++d) {
        const float f = fq[d];
        const float* wr = W + (size_t)(h * 256 + d) * 512;
        s0 += f * wr[t];
        s1 += f * wr[t + 256];
    }
    const size_t ro = (size_t)op * 512;
    WB[ro + t] = f2bf(s0);
    WB[ro + 256 + t] = f2bf(s1);
}

// ---------------- mega: G in LDS, kg + score fused ----------------
// grid (256, 2): x = row block (128 rows), y = head z. 512 threads, 8 waves.
__global__ __launch_bounds__(512)
void gemm_gkg(const short* __restrict__ capB,
              const short* __restrict__ WaB, const short* __restrict__ WbB,
              const float* __restrict__ ba, const float* __restrict__ bb,
              const short* __restrict__ Wfg2B, const float* __restrict__ bfg2,
              const short* __restrict__ WkB, const float* __restrict__ bk,
              const float* __restrict__ qg, float* __restrict__ scorep)
{
    __shared__ short smem[40960];   // 80 KB
    const int tid = threadIdx.x;
    const int bm = blockIdx.x * 128;
    const int z = blockIdx.y;
    const int lane = tid & 63;
    const int wv = tid >> 6;
    const int wr = wv >> 2, wc = wv & 3;         // 2 x 4 waves
    const int fr = lane & 15, kc = lane >> 4;
    const int r0 = tid >> 2;
    const int e0 = (((tid & 3) ^ ((r0 >> 1) & 3))) * 8;
    const int kce = (kc ^ ((fr >> 1) & 3)) * 8;

    const short* B1 = WaB + (size_t)z * 256 * 512;
    const short* B2 = WbB + (size_t)z * 256 * 512;

    // ---------- Phase A: acc1 = cap@Wa^T, acc2 = cap@Wb^T (K=512) ----------
    // staging: phase ph at smem[ph*20480]: A[128][32]@0, B1[256][32]@4096, B2@12288
    f32x4 acc1[4][4], acc2[4][4];
#pragma unroll
    for (int i = 0; i < 4; ++i)
#pragma unroll
        for (int j = 0; j < 4; ++j) {
            acc1[i][j] = (f32x4){0.f, 0.f, 0.f, 0.f};
            acc2[i][j] = (f32x4){0.f, 0.f, 0.f, 0.f};
        }

    auto stageA = [&](int ph, int k0) {
        short* s = smem + ph * 20480;
        glds16(capB + (size_t)(bm + r0) * 512 + k0 + e0, s + tid * 8);
        glds16(B1 + (size_t)r0 * 512 + k0 + e0,          s + 4096 + tid * 8);
        glds16(B1 + (size_t)(r0 + 128) * 512 + k0 + e0,  s + 4096 + (tid + 512) * 8);
        glds16(B2 + (size_t)r0 * 512 + k0 + e0,          s + 12288 + tid * 8);
        glds16(B2 + (size_t)(r0 + 128) * 512 + k0 + e0,  s + 12288 + (tid + 512) * 8);
    };

    stageA(0, 0);
    __syncthreads();
    for (int s = 0; s < 16; ++s) {
        if (s + 1 < 16) stageA((s + 1) & 1, (s + 1) * 32);
        const short* b = smem + (s & 1) * 20480;
        bf16x8 ah[4], bh[4];
#pragma unroll
        for (int i = 0; i < 4; ++i)
            ah[i] = *(const bf16x8*)&b[(wr * 64 + i * 16 + fr) * 32 + kce];
#pragma unroll
        for (int i = 0; i < 4; ++i)
            bh[i] = *(const bf16x8*)&b[4096 + (wc * 64 + i * 16 + fr) * 32 + kce];
#pragma unroll
        for (int mi = 0; mi < 4; ++mi)
#pragma unroll
            for (int ni = 0; ni < 4; ++ni)
                acc1[mi][ni] = __builtin_amdgcn_mfma_f32_16x16x32_bf16(ah[mi], bh[ni], acc1[mi][ni], 0, 0, 0);
#pragma unroll
        for (int i = 0; i < 4; ++i)
            bh[i] = *(const bf16x8*)&b[12288 + (wc * 64 + i * 16 + fr) * 32 + kce];
#pragma unroll
        for (int mi = 0; mi < 4; ++mi)
#pragma unroll
            for (int ni = 0; ni < 4; ++ni)
                acc2[mi][ni] = __builtin_amdgcn_mfma_f32_16x16x32_bf16(ah[mi], bh[ni], acc2[mi][ni], 0, 0, 0);
        __syncthreads();
    }

    // ---------- G -> LDS, swizzled [128][256] at smem[0..32768) ----------
    // store (row, col) at row*256 + ((col>>3)^((row>>1)&3))*8 + (col&7)
#pragma unroll
    for (int mi = 0; mi < 4; ++mi) {
#pragma unroll
        for (int ni = 0; ni < 4; ++ni) {
#pragma unroll
            for (int r = 0; r < 4; ++r) {
                const int row = wr * 64 + mi * 16 + kc * 4 + r;
                const int col = wc * 64 + ni * 16 + fr;
                const float g = (acc2[mi][ni][r] + bb[z * 256 + col])
                              * (acc1[mi][ni][r] + ba[z * 256 + col]);
                const int grp = (col >> 3) ^ ((row >> 1) & 3);
                smem[row * 256 + grp * 8 + (col & 7)] = f2bf(g);
            }
        }
    }
    __syncthreads();

    // ---------- Phase B: acc3 = G(LDS) @ Wfg2^T (K=256, single-buffered B) ----------
    f32x4 acc3[4][4];
#pragma unroll
    for (int i = 0; i < 4; ++i)
#pragma unroll
        for (int j = 0; j < 4; ++j) acc3[i][j] = (f32x4){0.f, 0.f, 0.f, 0.f};

    short* sB = smem + 32768;   // [256][32] = 8192 shorts
    for (int kk = 0; kk < 8; ++kk) {
        const int k0 = kk * 32;
        glds16(Wfg2B + (size_t)r0 * 256 + k0 + e0,         sB + tid * 8);
        glds16(Wfg2B + (size_t)(r0 + 128) * 256 + k0 + e0, sB + (tid + 512) * 8);
        __syncthreads();
        bf16x8 ah[4], bh[4];
#pragma unroll
        for (int i = 0; i < 4; ++i)
            ah[i] = *(const bf16x8*)&smem[(wr * 64 + i * 16 + fr) * 256 + k0 + kce];
#pragma unroll
        for (int i = 0; i < 4; ++i)
            bh[i] = *(const bf16x8*)&sB[(wc * 64 + i * 16 + fr) * 32 + kce];
#pragma unroll
        for (int mi = 0; mi < 4; ++mi)
#pragma unroll
            for (int ni = 0; ni < 4; ++ni)
                acc3[mi][ni] = __builtin_amdgcn_mfma_f32_16x16x32_bf16(ah[mi], bh[ni], acc3[mi][ni], 0, 0, 0);
        __syncthreads();
    }

    // ---------- Phase C: acc2 = cap @ Wk_h^T (K=512, double-buffered) ----------
    const short* BK = WkB + (size_t)z * 256 * 512;
#pragma unroll
    for (int i = 0; i < 4; ++i)
#pragma unroll
        for (int j = 0; j < 4; ++j) acc2[i][j] = (f32x4){0.f, 0.f, 0.f, 0.f};

    auto stageC = [&](int ph, int k0) {
        short* s = smem + ph * 12288;   // A[128][32]@0, B[256][32]@4096
        glds16(capB + (size_t)(bm + r0) * 512 + k0 + e0, s + tid * 8);
        glds16(BK + (size_t)r0 * 512 + k0 + e0,          s + 4096 + tid * 8);
        glds16(BK + (size_t)(r0 + 128) * 512 + k0 + e0,  s + 4096 + (tid + 512) * 8);
    };

    stageC(0, 0);
    __syncthreads();
    for (int s = 0; s < 16; ++s) {
        if (s + 1 < 16) stageC((s + 1) & 1, (s + 1) * 32);
        const short* b = smem + (s & 1) * 12288;
        bf16x8 ah[4], bh[4];
#pragma unroll
        for (int i = 0; i < 4; ++i)
            ah[i] = *(const bf16x8*)&b[(wr * 64 + i * 16 + fr) * 32 + kce];
#pragma unroll
        for (int i = 0; i < 4; ++i)
            bh[i] = *(const bf16x8*)&b[4096 + (wc * 64 + i * 16 + fr) * 32 + kce];
#pragma unroll
        for (int mi = 0; mi < 4; ++mi)
#pragma unroll
            for (int ni = 0; ni < 4; ++ni)
                acc2[mi][ni] = __builtin_amdgcn_mfma_f32_16x16x32_bf16(ah[mi], bh[ni], acc2[mi][ni], 0, 0, 0);
        __syncthreads();
    }

    // ---------- epilogue: score[b,z,j] = sum_c kg[j,c]*qg[b,z,c] ----------
    float qgv[4];
    float pt[4][4];
    const int b_ = bm >> 8;
#pragma unroll
    for (int ni = 0; ni < 4; ++ni)
        qgv[ni] = qg[b_ * 512 + z * 256 + wc * 64 + ni * 16 + fr];
#pragma unroll
    for (int mi = 0; mi < 4; ++mi)
#pragma unroll
        for (int r = 0; r < 4; ++r) pt[mi][r] = 0.f;

#pragma unroll
    for (int mi = 0; mi < 4; ++mi) {
#pragma unroll
        for (int ni = 0; ni < 4; ++ni) {
#pragma unroll
            for (int r = 0; r < 4; ++r) {
                const int col = wc * 64 + ni * 16 + fr;
                const float v = acc3[mi][ni][r] + bfg2[col];
                const float e = acc2[mi][ni][r] + bk[z * 256 + col];
                const float kgv = e / (1.f + expf(-v));
                pt[mi][r] += kgv * qgv[ni];
            }
        }
    }

    float (*sp)[4] = (float(*)[4])smem;   // staging dead; reuse
#pragma unroll
    for (int mi = 0; mi < 4; ++mi) {
#pragma unroll
        for (int r = 0; r < 4; ++r) {
            float p = pt[mi][r];
            p += __shfl_xor(p, 1);
            p += __shfl_xor(p, 2);
            p += __shfl_xor(p, 4);
            p += __shfl_xor(p, 8);
            if (fr == 0) {
                const int row_local = wr * 64 + mi * 16 + kc * 4 + r;
                sp[row_local][wc] = p;
            }
        }
    }
    __syncthreads();
    if (tid < 128) {
        const float s = sp[tid][0] + sp[tid][1] + sp[tid][2] + sp[tid][3];
        const int row = bm + tid;
        const int b = row >> 8, j = row & 255;
        scorep[(size_t)b * 512 + z * 256 + j] = s;
    }
}

// ---------------- qg at gathered rows: G computed in-kernel (fp32 acc) ----------------
__global__ __launch_bounds__(256)
void qg_kernel(const float* __restrict__ cap,
               const short* __restrict__ WaB, const short* __restrict__ WbB,
               const float* __restrict__ ba, const float* __restrict__ bb,
               const float* __restrict__ Wq, const float* __restrict__ bq,
               const float* __restrict__ Wfg, const float* __restrict__ bfg,
               const int* __restrict__ lengths, float* __restrict__ qg)
{
    __shared__ float cr[512];
    __shared__ float gs[256];
    const int b = blockIdx.x >> 1, h = blockIdx.x & 1;
    const int t = threadIdx.x;
    int r = lengths[b] - 1;
    if (r < 0) r = 0;
    if (r > 255) r = 255;
    const size_t base = ((size_t)b * 256 + r) * 512;
    cr[t] = cap[base + t];
    cr[t + 256] = cap[base + 256 + t];
    __syncthreads();
    // G[r, h*256+t] = (cap.Wb_row + bb) * (cap.Wa_row + ba)
    {
        const bf16x8* wa8 = (const bf16x8*)(WaB + (size_t)(h * 256 + t) * 512);
        const bf16x8* wb8 = (const bf16x8*)(WbB + (size_t)(h * 256 + t) * 512);
        float sa = 0.f, sb = 0.f;
        for (int k8 = 0; k8 < 64; ++k8) {
            bf16x8 wa = wa8[k8];
            bf16x8 wb = wb8[k8];
#pragma unroll
            for (int j = 0; j < 8; ++j) {
                const float c = cr[k8 * 8 + j];
                sa += bf2f(wa[j]) * c;
                sb += bf2f(wb[j]) * c;
            }
        }
        gs[t] = (sb + bb[h * 256 + t]) * (sa + ba[h * 256 + t]);
    }
    __syncthreads();
    // Q fp32 + gate
    const float4* wq4 = (const float4*)(Wq + (size_t)(h * 256 + t) * 512);
    float q = 0.f;
    for (int k4 = 0; k4 < 128; ++k4) {
        float4 w = wq4[k4];
        q += w.x * cr[k4 * 4 + 0] + w.y * cr[k4 * 4 + 1]
           + w.z * cr[k4 * 4 + 2] + w.w * cr[k4 * 4 + 3];
    }
    q += bq[h * 256 + t];
    const float4* w4 = (const float4*)(Wfg + (size_t)t * 256);
    float a = 0.f;
    for (int k4 = 0; k4 < 64; ++k4) {
        float4 w = w4[k4];
        a += w.x * gs[k4 * 4 + 0] + w.y * gs[k4 * 4 + 1]
           + w.z * gs[k4 * 4 + 2] + w.w * gs[k4 * 4 + 3];
    }
    a += bfg[t];
    qg[b * 512 + h * 256 + t] = q / (1.f + expf(-a));
}

// ---------------- softmax (inline) + pbar from bf16 cap ----------------
// scorep layout: [b*512 + h*256 + j]
__global__ __launch_bounds__(256)
void pbar_kernel(const float* __restrict__ scorep, const short* __restrict__ capB,
                 float* __restrict__ pbar)
{
    __shared__ float sc[512], red[512];
    const int b = blockIdx.y, cg = blockIdx.x;
    const int t = threadIdx.x;
#pragma unroll
    for (int i = 0; i < 2; ++i) {
        const int o = t + i * 256;
        sc[o] = floorf(scorep[(size_t)b * 512 + o] * 0.0625f);
    }
    __syncthreads();
    red[t] = sc[t]; red[t + 256] = sc[t + 256];
    __syncthreads();
    for (int s = 128; s > 0; s >>= 1) {
        if (t < s) {
            red[t] = fmaxf(red[t], red[t + s]);
            red[256 + t] = fmaxf(red[256 + t], red[256 + t + s]);
        }
        __syncthreads();
    }
    const float mx0 = red[0], mx1 = red[256];
    __syncthreads();
    const float e0 = expf(sc[t] - mx0);
    const float e1 = expf(sc[t + 256] - mx1);
    red[t] = e0; red[t + 256] = e1;
    __syncthreads();
    for (int s = 128; s > 0; s >>= 1) {
        if (t < s) { red[t] += red[t + s]; red[256 + t] += red[256 + t + s]; }
        __syncthreads();
    }
    sc[t] = e0 / red[0];
    sc[t + 256] = e1 / red[256];
    __syncthreads();

    const int c = cg * 64 + (t & 63);
    const int jg = t >> 6;
    float a0 = 0.f, a1 = 0.f;
    for (int j = jg * 64; j < jg * 64 + 64; ++j) {
        const float cv = bf2f(capB[((size_t)(b * 256 + j)) * 512 + c]);
        a0 += sc[j] * cv;
        a1 += sc[256 + j] * cv;
    }
    red[t] = a0;
    __syncthreads();
    if (t < 64) {
        const float s0 = red[t] + red[t + 64] + red[t + 128] + red[t + 192];
        pbar[b * 1024 + cg * 64 + t] = s0;
    }
    __syncthreads();
    red[t] = a1;
    __syncthreads();
    if (t < 64) {
        const float s1 = red[t] + red[t + 64] + red[t + 128] + red[t + 192];
        pbar[b * 1024 + 512 + cg * 64 + t] = s1;
    }
}

// ---------------- x = pbar@Wv^T + bv, BN1, residual ----------------
__global__ __launch_bounds__(256)
void bnx_kernel(const float* __restrict__ pbar, const float* __restrict__ cap,
                const int* __restrict__ lengths,
                const float* __restrict__ Wv, const float* __restrict__ bv,
                const float* __restrict__ g1, const float* __restrict__ b1,
                const float* __restrict__ m1, const float* __restrict__ v1,
                float* __restrict__ xga)
{
    __shared__ float pb[1024];
    const int b = blockIdx.x;
    const int t = threadIdx.x;
    int r = lengths[b] - 1;
    if (r < 0) r = 0;
    if (r > 255) r = 255;
    const size_t base = ((size_t)b * 256 + r) * 512;
    pb[t] = pbar[b * 1024 + t];
    pb[t + 256] = pbar[b * 1024 + 256 + t];
    pb[t + 512] = pbar[b * 1024 + 512 + t];
    pb[t + 768] = pbar[b * 1024 + 768 + t];
    __syncthreads();
    float x0 = 0.f, x1 = 0.f;
    {
        const float4* w4 = (const float4*)(Wv + (size_t)t * 512);
        for (int k4 = 0; k4 < 128; ++k4) {
            float4 w = w4[k4];
            x0 += w.x * pb[k4 * 4 + 0] + w.y * pb[k4 * 4 + 1]
                + w.z * pb[k4 * 4 + 2] + w.w * pb[k4 * 4 + 3];
        }
        x0 += bv[t];
    }
    {
        const float4* w4 = (const float4*)(Wv + (size_t)(t + 256) * 512);
        for (int k4 = 0; k4 < 128; ++k4) {
            float4 w = w4[k4];
            x1 += w.x * pb[512 + k4 * 4 + 0] + w.y * pb[512 + k4 * 4 + 1]
                + w.z * pb[512 + k4 * 4 + 2] + w.w * pb[512 + k4 * 4 + 3];
        }
        x1 += bv[t + 256];
    }
    const int c0 = t, c1 = t + 256;
    const float s0 = g1[c0] / sqrtf(v1[c0] + 1e-5f);
    const float s1 = g1[c1] / sqrtf(v1[c1] + 1e-5f);
    xga[b * 512 + c0] = cap[base + c0] + (x0 - m1[c0]) * s0 + b1[c0];
    xga[b * 512 + c1] = cap[base + c1] + (x1 - m1[c1]) * s1 + b1[c1];
}

// ---------------- MLP strip GEMMs (weights read once) ----------------
__global__ __launch_bounds__(256)
void mlp1(const float* __restrict__ xga, const float* __restrict__ W,
          const float* __restrict__ bias, float* __restrict__ hid)
{
    __shared__ float xs[16 * 512];
    const int r0 = blockIdx.y * 16;
    const int c0 = blockIdx.x * 64;
    for (int i = threadIdx.x; i < 2048; i += 256)
        ((float4*)xs)[i] = ((const float4*)(xga + (size_t)r0 * 512))[i];
    __syncthreads();
    const int col = c0 + (threadIdx.x & 63);
    const int rg = (threadIdx.x >> 6) * 4;
    float acc[4] = {0.f, 0.f, 0.f, 0.f};
    const float4* w4 = (const float4*)(W + (size_t)col * 512);
    for (int k4 = 0; k4 < 128; ++k4) {
        float4 w = w4[k4];
#pragma unroll
        for (int rr = 0; rr < 4; ++rr) {
            float4 x = *(const float4*)&xs[(rg + rr) * 512 + k4 * 4];
            acc[rr] += w.x * x.x + w.y * x.y + w.z * x.z + w.w * x.w;
        }
    }
    const float bb = bias[col];
#pragma unroll
    for (int rr = 0; rr < 4; ++rr)
        hid[(size_t)(r0 + rg + rr) * 1024 + col] = fmaxf(acc[rr] + bb, 0.f);
}

__global__ __launch_bounds__(256)
void mlp2(const float* __restrict__ hid, const float* __restrict__ W,
          const float* __restrict__ bias, const float* __restrict__ xga,
          float* __restrict__ tex)
{
    __shared__ float xs[16 * 1024];
    const int r0 = blockIdx.y * 16;
    const int c0 = blockIdx.x * 64;
    for (int i = threadIdx.x; i < 4096; i += 256)
        ((float4*)xs)[i] = ((const float4*)(hid + (size_t)r0 * 1024))[i];
    __syncthreads();
    const int col = c0 + (threadIdx.x & 63);
    const int rg = (threadIdx.x >> 6) * 4;
    float acc[4] = {0.f, 0.f, 0.f, 0.f};
    const float4* w4 = (const float4*)(W + (size_t)col * 1024);
    for (int k4 = 0; k4 < 256; ++k4) {
        float4 w = w4[k4];
#pragma unroll
        for (int rr = 0; rr < 4; ++rr) {
            float4 x = *(const float4*)&xs[(rg + rr) * 1024 + k4 * 4];
            acc[rr] += w.x * x.x + w.y * x.y + w.z * x.z + w.w * x.w;
        }
    }
    const float bb = bias[col];
#pragma unroll
    for (int rr = 0; rr < 4; ++rr) {
        const int row = r0 + rg + rr;
        tex[(size_t)row * 512 + col] = acc[rr] + bb + xga[(size_t)row * 512 + col];
    }
}

__global__ __launch_bounds__(256)
void norm_out(const float* __restrict__ tex, float* __restrict__ out)
{
    __shared__ float red[256];
    const int b = blockIdx.x;
    const int t = threadIdx.x;
    const float a = tex[b * 512 + t];
    const float c = tex[b * 512 + 256 + t];
    red[t] = a * a + c * c;
    __syncthreads();
    for (int s = 128; s > 0; s >>= 1) {
        if (t < s) red[t] += red[t + s];
        __syncthreads();
    }
    const float inv = 1.f / (sqrtf(red[0]) + 1e-8f);
    out[b * 512 + t] = a * inv;
    out[b * 512 + 256 + t] = c * inv;
}

extern "C" void kernel_launch(void* const* d_in, const int* in_sizes, int n_in,
                              void* d_out, int out_size, void* d_ws, size_t ws_size,
                              hipStream_t stream)
{
    const float* cap = (const float*)d_in[0];
    const int* lengths = (const int*)d_in[1];
    const float* Wq  = (const float*)d_in[2];
    const float* Wk  = (const float*)d_in[3];
    const float* Wv  = (const float*)d_in[4];
    const float* bq  = (const float*)d_in[5];
    const float* bk  = (const float*)d_in[6];
    const float* bv  = (const float*)d_in[7];
    const float* Wfq = (const float*)d_in[8];
    const float* bfq = (const float*)d_in[9];
    const float* Wfk = (const float*)d_in[10];
    const float* bfk = (const float*)d_in[11];
    const float* Wfg = (const float*)d_in[12];
    const float* bfg = (const float*)d_in[13];
    const float* g1  = (const float*)d_in[14];
    const float* b1  = (const float*)d_in[15];
    const float* m1  = (const float*)d_in[16];
    const float* v1  = (const float*)d_in[17];
    const float* Wm1 = (const float*)d_in[30];
    const float* bm1 = (const float*)d_in[31];
    const float* Wm2 = (const float*)d_in[32];
    const float* bm2 = (const float*)d_in[33];
    float* out = (float*)d_out;

    char* w = (char*)d_ws;
    const size_t MB = 1024 * 1024;
    short* capB = (short*)(w);                 // 32MB bf16 cap (valid throughout)
    char* wp = w + 32 * MB;
    short* WkB   = (short*)wp; wp += 524288;   // [512,512] (phase C B)
    short* WaB   = (short*)wp; wp += 524288;   // composed Wfq@Wq_h
    short* WbB   = (short*)wp; wp += 524288;   // composed Wfk@Wk_h
    short* Wfg2B = (short*)wp; wp += 131072;
    float* ba     = (float*)wp; wp += 2048;
    float* bb     = (float*)wp; wp += 2048;
    float* qg     = (float*)wp; wp += 262144;
    float* scorep = (float*)wp; wp += 262144;   // [128][2][256]
    float* pbar   = (float*)wp; wp += 524288;
    float* xga    = (float*)wp; wp += 262144;
    float* hid    = (float*)wp; wp += 524288;
    float* tex    = (float*)wp; wp += 262144;

    // 1. bf16 casts: cap, Wk, Wfg2
    CastArgs ca;
    ca.src[0] = cap;          ca.dst[0] = capB;  ca.n4[0] = 4194304;
    ca.src[1] = Wk;           ca.dst[1] = WkB;   ca.n4[1] = 65536;
    ca.src[2] = Wfg + 65536;  ca.dst[2] = Wfg2B; ca.n4[2] = 16384;
    cast_multi<<<dim3(4096, 3), 256, 0, stream>>>(ca);

    // 2. composed Wa/ba and Wb/bb
    compose2<<<dim3(512, 2), 256, 0, stream>>>(Wq, bq, Wfq, bfq, Wk, bk, Wfk, bfk,
                                               WaB, ba, WbB, bb);

    // 3. qg at gathered rows (computes its own G; independent of mega)
    qg_kernel<<<dim3(256), 256, 0, stream>>>(cap, WaB, WbB, ba, bb,
                                             Wq, bq, Wfg, bfg, lengths, qg);

    // 4. mega: G in LDS + kg + fused scores
    gemm_gkg<<<dim3(256, 2), 512, 0, stream>>>(capB, WaB, WbB, ba, bb,
                                               Wfg2B, bfg + 256, WkB, bk, qg, scorep);

    // 5-6. softmax+pbar (bf16 cap), BN/residual
    pbar_kernel<<<dim3(8, 128), 256, 0, stream>>>(scorep, capB, pbar);
    bnx_kernel<<<dim3(128), 256, 0, stream>>>(pbar, cap, lengths, Wv, bv, g1, b1, m1, v1, xga);

    // 7-9. MLP, norm
    mlp1<<<dim3(16, 8), 256, 0, stream>>>(xga, Wm1, bm1, hid);
    mlp2<<<dim3(8, 8), 256, 0, stream>>>(hid, Wm2, bm2, xga, tex);
    norm_out<<<dim3(128), 256, 0, stream>>>(tex, out);
}

// Round 18
// 269.337 us; speedup vs baseline: 1.0273x; 1.0273x over previous
//
#include <hip/hip_runtime.h>
#include <math.h>

// BS=128, L=256, D=512, H=2, DK=256.
// Conv branches dead (gather idx < 256). ALL GEMMs 1-pass bf16 MFMA, 2-phase
// __syncthreads-only. Compositions: Wa = Wfq@Wq_h, Wb = Wfk@Wk_h (both
// gate-shielded). G = (cap@Wb^T+bb)*(cap@Wa^T+ba). K never stored (fp32 in
// kg epilogue). V GEMM removed via x=(p@cap)@Wv^T+bv. kg GEMM: its two
// kloops (G@Wfg2, cap@Wk) interleaved into one 16-chunk loop (24->16
// barriers, 24 avg MFMA/barrier).

typedef short bf16x8 __attribute__((ext_vector_type(8)));
typedef float f32x4 __attribute__((ext_vector_type(4)));
typedef short short4v __attribute__((ext_vector_type(4)));

__device__ __forceinline__ short f2bf(float x) {
    union { float f; unsigned u; } c; c.f = x;
    unsigned r = c.u + 0x7FFFu + ((c.u >> 16) & 1u);
    return (short)(r >> 16);
}
__device__ __forceinline__ float bf2f(short h) {
    union { float f; unsigned u; } c; c.u = ((unsigned)(unsigned short)h) << 16;
    return c.f;
}
__device__ __forceinline__ void glds16(const void* g, void* l) {
    __builtin_amdgcn_global_load_lds(
        (const __attribute__((address_space(1))) void*)g,
        (__attribute__((address_space(3))) void*)l, 16, 0, 0);
}

// ---------------- cast fp32 -> bf16 ----------------
struct CastArgs {
    const float* src[3];
    short* dst[3];
    int n4[3];
};
__global__ __launch_bounds__(256) void cast_multi(CastArgs a)
{
    const int j = blockIdx.y;
    const float4* s = (const float4*)a.src[j];
    short* d = a.dst[j];
    const int n4 = a.n4[j];
    for (int i = blockIdx.x * 256 + threadIdx.x; i < n4; i += gridDim.x * 256) {
        float4 x = s[i];
        short4v h;
        h.x = f2bf(x.x); h.y = f2bf(x.y); h.z = f2bf(x.z); h.w = f2bf(x.w);
        *(short4v*)&d[i * 4] = h;
    }
}

// ---------------- composed weights: W∘ = F @ W_h (bf16), b∘ = F@b_h + bf ----
__global__ __launch_bounds__(256)
void compose2(const float* __restrict__ Wq, const float* __restrict__ bq,
              const float* __restrict__ Wfq, const float* __restrict__ bfq,
              const float* __restrict__ Wk, const float* __restrict__ bk,
              const float* __restrict__ Wfk, const float* __restrict__ bfk,
              short* __restrict__ WaB, float* __restrict__ ba,
              short* __restrict__ WbB, float* __restrict__ bb)
{
    __shared__ float fq[256];
    __shared__ float redc[256];
    const int op = blockIdx.x;          // 0..511: h = op>>8, o = op&255
    const int h = op >> 8, o = op & 255;
    const int t = threadIdx.x;
    const bool second = (blockIdx.y == 1);
    const float* W  = second ? Wk  : Wq;
    const float* bv = second ? bk  : bq;
    const float* F  = second ? Wfk : Wfq;
    const float* bf = second ? bfk : bfq;
    short* WB   = second ? WbB : WaB;
    float* bout = second ? bb  : ba;

    fq[t] = F[o * 256 + t];
    redc[t] = fq[t] * bv[h * 256 + t];
    __syncthreads();
    for (int s = 128; s > 0; s >>= 1) {
        if (t < s) redc[t] += redc[t + s];
        __syncthreads();
    }
    if (t == 0) bout[op] = redc[0] + bf[o];
    float s0 = 0.f, s1 = 0.f;
    for (int d = 0; d < 256; ++d) {
        const float f = fq[d];
        const float* wr = W + (size_t)(h * 256 + d) * 512;
        s0 += f * wr[t];
        s1 += f * wr[t + 256];
    }
    const size_t ro = (size_t)op * 512;
    WB[ro + t] = f2bf(s0);
    WB[ro + 256 + t] = f2bf(s1);
}

// ---------------- G: dual-B 2-phase, G = (cap@Wb^T+bb)*(cap@Wa^T+ba) ----------------
__global__ __launch_bounds__(256, 2)
void gemm_g(const short* __restrict__ capB,
            const short* __restrict__ WaB, const short* __restrict__ WbB,
            const float* __restrict__ ba, const float* __restrict__ bb,
            short* __restrict__ Gbuf)
{
    __shared__ short lds[2][12288];   // A 8KB | B1 8KB | B2 8KB per phase
    const int tid = threadIdx.x;
    const int bm = blockIdx.y * 128;
    const int bn = blockIdx.x * 128;   // within-head col block
    const int z = blockIdx.z;
    const short* B1 = WaB + (size_t)z * 256 * 512;
    const short* B2 = WbB + (size_t)z * 256 * 512;

    const int lane = tid & 63;
    const int wr = (tid >> 7) & 1, wc = (tid >> 6) & 1;
    const int fr = lane & 15, kc = lane >> 4;
    const int r0 = tid >> 2;
    const int e0 = (((tid & 3) ^ ((r0 >> 1) & 3))) * 8;
    const int kce = (kc ^ ((fr >> 1) & 3)) * 8;

    auto stage = [&](int ph, int k0) {
        short* b = lds[ph];
        glds16(capB + (size_t)(bm + r0) * 512 + k0 + e0,      b + tid * 8);
        glds16(capB + (size_t)(bm + r0 + 64) * 512 + k0 + e0, b + (tid + 256) * 8);
        glds16(B1 + (size_t)(bn + r0) * 512 + k0 + e0,        b + 4096 + tid * 8);
        glds16(B1 + (size_t)(bn + r0 + 64) * 512 + k0 + e0,   b + 4096 + (tid + 256) * 8);
        glds16(B2 + (size_t)(bn + r0) * 512 + k0 + e0,        b + 8192 + tid * 8);
        glds16(B2 + (size_t)(bn + r0 + 64) * 512 + k0 + e0,   b + 8192 + (tid + 256) * 8);
    };

    f32x4 acc1[4][4], acc2[4][4];
#pragma unroll
    for (int i = 0; i < 4; ++i)
#pragma unroll
        for (int j = 0; j < 4; ++j) {
            acc1[i][j] = (f32x4){0.f, 0.f, 0.f, 0.f};
            acc2[i][j] = (f32x4){0.f, 0.f, 0.f, 0.f};
        }

    stage(0, 0);
    __syncthreads();
    for (int s = 0; s < 16; ++s) {
        if (s + 1 < 16) stage((s + 1) & 1, (s + 1) * 32);
        const short* b = lds[s & 1];
        bf16x8 ah[4], bh[4];
#pragma unroll
        for (int i = 0; i < 4; ++i)
            ah[i] = *(const bf16x8*)&b[(wr * 64 + i * 16 + fr) * 32 + kce];
#pragma unroll
        for (int i = 0; i < 4; ++i)
            bh[i] = *(const bf16x8*)&b[4096 + (wc * 64 + i * 16 + fr) * 32 + kce];
#pragma unroll
        for (int mi = 0; mi < 4; ++mi)
#pragma unroll
            for (int ni = 0; ni < 4; ++ni)
                acc1[mi][ni] = __builtin_amdgcn_mfma_f32_16x16x32_bf16(ah[mi], bh[ni], acc1[mi][ni], 0, 0, 0);
#pragma unroll
        for (int i = 0; i < 4; ++i)
            bh[i] = *(const bf16x8*)&b[8192 + (wc * 64 + i * 16 + fr) * 32 + kce];
#pragma unroll
        for (int mi = 0; mi < 4; ++mi)
#pragma unroll
            for (int ni = 0; ni < 4; ++ni)
                acc2[mi][ni] = __builtin_amdgcn_mfma_f32_16x16x32_bf16(ah[mi], bh[ni], acc2[mi][ni], 0, 0, 0);
        __syncthreads();
    }

#pragma unroll
    for (int mi = 0; mi < 4; ++mi) {
#pragma unroll
        for (int ni = 0; ni < 4; ++ni) {
#pragma unroll
            for (int r = 0; r < 4; ++r) {
                const int row = bm + wr * 64 + mi * 16 + kc * 4 + r;
                const int col = bn + wc * 64 + ni * 16 + fr;
                const float av  = acc1[mi][ni][r] + ba[z * 256 + col];
                const float lin = acc2[mi][ni][r] + bb[z * 256 + col];
                Gbuf[(size_t)row * 512 + z * 256 + col] = f2bf(lin * av);
            }
        }
    }
}

// ---------------- kg: interleaved dual kloop + fused score partials ----------------
// acc1 = G_h @ Wfg2^T (K=256, chunks 0-7); acc2 = cap @ Wk_h^T (K=512, all 16)
__global__ __launch_bounds__(256, 2)
void gemm_kg(const short* __restrict__ Gbuf,
             const short* __restrict__ Wfg2B, const float* __restrict__ bias,
             const short* __restrict__ capB,
             const short* __restrict__ WkB, const float* __restrict__ bk,
             const float* __restrict__ qg, float* __restrict__ scorep)
{
    __shared__ short lds[2][16384];   // G@0 | Wfg2@4096 | cap@8192 | Wk@12288
    __shared__ float sp[256];
    const int tid = threadIdx.x;
    const int bm = blockIdx.y * 128;
    const int bn = blockIdx.x * 128;
    const int z = blockIdx.z;
    const short* A1 = Gbuf + (size_t)z * 256;
    const short* B2 = WkB + (size_t)z * 256 * 512;

    const int lane = tid & 63;
    const int wr = (tid >> 7) & 1, wc = (tid >> 6) & 1;
    const int fr = lane & 15, kc = lane >> 4;
    const int r0 = tid >> 2;
    const int e0 = (((tid & 3) ^ ((r0 >> 1) & 3))) * 8;
    const int kce = (kc ^ ((fr >> 1) & 3)) * 8;

    auto stage = [&](int ph, int s) {
        short* b = lds[ph];
        const int k0 = s * 32;
        glds16(capB + (size_t)(bm + r0) * 512 + k0 + e0,      b + 8192 + tid * 8);
        glds16(capB + (size_t)(bm + r0 + 64) * 512 + k0 + e0, b + 8192 + (tid + 256) * 8);
        glds16(B2 + (size_t)(bn + r0) * 512 + k0 + e0,        b + 12288 + tid * 8);
        glds16(B2 + (size_t)(bn + r0 + 64) * 512 + k0 + e0,   b + 12288 + (tid + 256) * 8);
        if (s < 8) {
            glds16(A1 + (size_t)(bm + r0) * 512 + k0 + e0,        b + tid * 8);
            glds16(A1 + (size_t)(bm + r0 + 64) * 512 + k0 + e0,   b + (tid + 256) * 8);
            glds16(Wfg2B + (size_t)(bn + r0) * 256 + k0 + e0,     b + 4096 + tid * 8);
            glds16(Wfg2B + (size_t)(bn + r0 + 64) * 256 + k0 + e0, b + 4096 + (tid + 256) * 8);
        }
    };

    f32x4 acc1[4][4], acc2[4][4];
#pragma unroll
    for (int i = 0; i < 4; ++i)
#pragma unroll
        for (int j = 0; j < 4; ++j) {
            acc1[i][j] = (f32x4){0.f, 0.f, 0.f, 0.f};
            acc2[i][j] = (f32x4){0.f, 0.f, 0.f, 0.f};
        }

    stage(0, 0);
    __syncthreads();
    for (int s = 0; s < 16; ++s) {
        if (s + 1 < 16) stage((s + 1) & 1, s + 1);
        const short* b = lds[s & 1];
        bf16x8 ah[4], bh[4];
#pragma unroll
        for (int i = 0; i < 4; ++i)
            ah[i] = *(const bf16x8*)&b[8192 + (wr * 64 + i * 16 + fr) * 32 + kce];
#pragma unroll
        for (int i = 0; i < 4; ++i)
            bh[i] = *(const bf16x8*)&b[12288 + (wc * 64 + i * 16 + fr) * 32 + kce];
#pragma unroll
        for (int mi = 0; mi < 4; ++mi)
#pragma unroll
            for (int ni = 0; ni < 4; ++ni)
                acc2[mi][ni] = __builtin_amdgcn_mfma_f32_16x16x32_bf16(ah[mi], bh[ni], acc2[mi][ni], 0, 0, 0);
        if (s < 8) {
#pragma unroll
            for (int i = 0; i < 4; ++i)
                ah[i] = *(const bf16x8*)&b[(wr * 64 + i * 16 + fr) * 32 + kce];
#pragma unroll
            for (int i = 0; i < 4; ++i)
                bh[i] = *(const bf16x8*)&b[4096 + (wc * 64 + i * 16 + fr) * 32 + kce];
#pragma unroll
            for (int mi = 0; mi < 4; ++mi)
#pragma unroll
                for (int ni = 0; ni < 4; ++ni)
                    acc1[mi][ni] = __builtin_amdgcn_mfma_f32_16x16x32_bf16(ah[mi], bh[ni], acc1[mi][ni], 0, 0, 0);
        }
        __syncthreads();
    }

    float qgv[4];
    float pt[4][4];
    {
        const int b = bm >> 8;
#pragma unroll
        for (int ni = 0; ni < 4; ++ni)
            qgv[ni] = qg[b * 512 + z * 256 + bn + wc * 64 + ni * 16 + fr];
#pragma unroll
        for (int mi = 0; mi < 4; ++mi)
#pragma unroll
            for (int r = 0; r < 4; ++r) pt[mi][r] = 0.f;
    }

#pragma unroll
    for (int mi = 0; mi < 4; ++mi) {
#pragma unroll
        for (int ni = 0; ni < 4; ++ni) {
#pragma unroll
            for (int r = 0; r < 4; ++r) {
                const int col = bn + wc * 64 + ni * 16 + fr;
                const float v = acc1[mi][ni][r] + bias[col];
                const float e = acc2[mi][ni][r] + bk[z * 256 + col];
                const float kgv = e / (1.f + expf(-v));
                pt[mi][r] += kgv * qgv[ni];
            }
        }
    }

#pragma unroll
    for (int mi = 0; mi < 4; ++mi) {
#pragma unroll
        for (int r = 0; r < 4; ++r) {
            float p = pt[mi][r];
            p += __shfl_xor(p, 1);
            p += __shfl_xor(p, 2);
            p += __shfl_xor(p, 4);
            p += __shfl_xor(p, 8);
            if (fr == 0) {
                const int row_local = wr * 64 + mi * 16 + kc * 4 + r;
                sp[row_local * 2 + wc] = p;
            }
        }
    }
    __syncthreads();
    if (tid < 128) {
        const int row = bm + tid;
        const float s = sp[tid * 2] + sp[tid * 2 + 1];
        const int b = row >> 8, j = row & 255;
        scorep[((size_t)(b * 2 + z) * 256 + j) * 2 + blockIdx.x] = s;
    }
}

// ---------------- qg at gathered rows: Q fp32-exact from cap ----------------
__global__ __launch_bounds__(256)
void qg_kernel(const float* __restrict__ cap,
               const short* __restrict__ Gbuf,
               const float* __restrict__ Wq, const float* __restrict__ bq,
               const float* __restrict__ Wfg, const float* __restrict__ bfg,
               const int* __restrict__ lengths, float* __restrict__ qg)
{
    __shared__ float cr[512];
    __shared__ float gs[256];
    const int b = blockIdx.x >> 1, h = blockIdx.x & 1;
    const int t = threadIdx.x;
    int r = lengths[b] - 1;
    if (r < 0) r = 0;
    if (r > 255) r = 255;
    const size_t base = ((size_t)b * 256 + r) * 512;
    cr[t] = cap[base + t];
    cr[t + 256] = cap[base + 256 + t];
    gs[t] = bf2f(Gbuf[base + h * 256 + t]);
    __syncthreads();
    const float4* wq4 = (const float4*)(Wq + (size_t)(h * 256 + t) * 512);
    float q = 0.f;
    for (int k4 = 0; k4 < 128; ++k4) {
        float4 w = wq4[k4];
        q += w.x * cr[k4 * 4 + 0] + w.y * cr[k4 * 4 + 1]
           + w.z * cr[k4 * 4 + 2] + w.w * cr[k4 * 4 + 3];
    }
    q += bq[h * 256 + t];
    const float4* w4 = (const float4*)(Wfg + (size_t)t * 256);
    float a = 0.f;
    for (int k4 = 0; k4 < 64; ++k4) {
        float4 w = w4[k4];
        a += w.x * gs[k4 * 4 + 0] + w.y * gs[k4 * 4 + 1]
           + w.z * gs[k4 * 4 + 2] + w.w * gs[k4 * 4 + 3];
    }
    a += bfg[t];
    qg[b * 512 + h * 256 + t] = q / (1.f + expf(-a));
}

// ---------------- softmax (inline) + pbar from bf16 cap ----------------
__global__ __launch_bounds__(256)
void pbar_kernel(const float* __restrict__ scorep, const short* __restrict__ capB,
                 float* __restrict__ pbar)
{
    __shared__ float sc[512], red[512];
    const int b = blockIdx.y, cg = blockIdx.x;
    const int t = threadIdx.x;
#pragma unroll
    for (int i = 0; i < 2; ++i) {
        const int o = t + i * 256;
        const int h = o >> 8, j = o & 255;
        const size_t si = ((size_t)(b * 2 + h) * 256 + j) * 2;
        sc[o] = floorf((scorep[si] + scorep[si + 1]) * 0.0625f);
    }
    __syncthreads();
    red[t] = sc[t]; red[t + 256] = sc[t + 256];
    __syncthreads();
    for (int s = 128; s > 0; s >>= 1) {
        if (t < s) {
            red[t] = fmaxf(red[t], red[t + s]);
            red[256 + t] = fmaxf(red[256 + t], red[256 + t + s]);
        }
        __syncthreads();
    }
    const float mx0 = red[0], mx1 = red[256];
    __syncthreads();
    const float e0 = expf(sc[t] - mx0);
    const float e1 = expf(sc[t + 256] - mx1);
    red[t] = e0; red[t + 256] = e1;
    __syncthreads();
    for (int s = 128; s > 0; s >>= 1) {
        if (t < s) { red[t] += red[t + s]; red[256 + t] += red[256 + t + s]; }
        __syncthreads();
    }
    sc[t] = e0 / red[0];
    sc[t + 256] = e1 / red[256];
    __syncthreads();

    const int c = cg * 64 + (t & 63);
    const int jg = t >> 6;
    float a0 = 0.f, a1 = 0.f;
    for (int j = jg * 64; j < jg * 64 + 64; ++j) {
        const float cv = bf2f(capB[((size_t)(b * 256 + j)) * 512 + c]);
        a0 += sc[j] * cv;
        a1 += sc[256 + j] * cv;
    }
    red[t] = a0;
    __syncthreads();
    if (t < 64) {
        const float s0 = red[t] + red[t + 64] + red[t + 128] + red[t + 192];
        pbar[b * 1024 + cg * 64 + t] = s0;
    }
    __syncthreads();
    red[t] = a1;
    __syncthreads();
    if (t < 64) {
        const float s1 = red[t] + red[t + 64] + red[t + 128] + red[t + 192];
        pbar[b * 1024 + 512 + cg * 64 + t] = s1;
    }
}

// ---------------- x = pbar@Wv^T + bv, BN1, residual ----------------
__global__ __launch_bounds__(256)
void bnx_kernel(const float* __restrict__ pbar, const float* __restrict__ cap,
                const int* __restrict__ lengths,
                const float* __restrict__ Wv, const float* __restrict__ bv,
                const float* __restrict__ g1, const float* __restrict__ b1,
                const float* __restrict__ m1, const float* __restrict__ v1,
                float* __restrict__ xga)
{
    __shared__ float pb[1024];
    const int b = blockIdx.x;
    const int t = threadIdx.x;
    int r = lengths[b] - 1;
    if (r < 0) r = 0;
    if (r > 255) r = 255;
    const size_t base = ((size_t)b * 256 + r) * 512;
    pb[t] = pbar[b * 1024 + t];
    pb[t + 256] = pbar[b * 1024 + 256 + t];
    pb[t + 512] = pbar[b * 1024 + 512 + t];
    pb[t + 768] = pbar[b * 1024 + 768 + t];
    __syncthreads();
    float x0 = 0.f, x1 = 0.f;
    {
        const float4* w4 = (const float4*)(Wv + (size_t)t * 512);
        for (int k4 = 0; k4 < 128; ++k4) {
            float4 w = w4[k4];
            x0 += w.x * pb[k4 * 4 + 0] + w.y * pb[k4 * 4 + 1]
                + w.z * pb[k4 * 4 + 2] + w.w * pb[k4 * 4 + 3];
        }
        x0 += bv[t];
    }
    {
        const float4* w4 = (const float4*)(Wv + (size_t)(t + 256) * 512);
        for (int k4 = 0; k4 < 128; ++k4) {
            float4 w = w4[k4];
            x1 += w.x * pb[512 + k4 * 4 + 0] + w.y * pb[512 + k4 * 4 + 1]
                + w.z * pb[512 + k4 * 4 + 2] + w.w * pb[512 + k4 * 4 + 3];
        }
        x1 += bv[t + 256];
    }
    const int c0 = t, c1 = t + 256;
    const float s0 = g1[c0] / sqrtf(v1[c0] + 1e-5f);
    const float s1 = g1[c1] / sqrtf(v1[c1] + 1e-5f);
    xga[b * 512 + c0] = cap[base + c0] + (x0 - m1[c0]) * s0 + b1[c0];
    xga[b * 512 + c1] = cap[base + c1] + (x1 - m1[c1]) * s1 + b1[c1];
}

// ---------------- MLP strip GEMMs (weights read once) ----------------
__global__ __launch_bounds__(256)
void mlp1(const float* __restrict__ xga, const float* __restrict__ W,
          const float* __restrict__ bias, float* __restrict__ hid)
{
    __shared__ float xs[16 * 512];
    const int r0 = blockIdx.y * 16;
    const int c0 = blockIdx.x * 64;
    for (int i = threadIdx.x; i < 2048; i += 256)
        ((float4*)xs)[i] = ((const float4*)(xga + (size_t)r0 * 512))[i];
    __syncthreads();
    const int col = c0 + (threadIdx.x & 63);
    const int rg = (threadIdx.x >> 6) * 4;
    float acc[4] = {0.f, 0.f, 0.f, 0.f};
    const float4* w4 = (const float4*)(W + (size_t)col * 512);
    for (int k4 = 0; k4 < 128; ++k4) {
        float4 w = w4[k4];
#pragma unroll
        for (int rr = 0; rr < 4; ++rr) {
            float4 x = *(const float4*)&xs[(rg + rr) * 512 + k4 * 4];
            acc[rr] += w.x * x.x + w.y * x.y + w.z * x.z + w.w * x.w;
        }
    }
    const float bb = bias[col];
#pragma unroll
    for (int rr = 0; rr < 4; ++rr)
        hid[(size_t)(r0 + rg + rr) * 1024 + col] = fmaxf(acc[rr] + bb, 0.f);
}

__global__ __launch_bounds__(256)
void mlp2(const float* __restrict__ hid, const float* __restrict__ W,
          const float* __restrict__ bias, const float* __restrict__ xga,
          float* __restrict__ tex)
{
    __shared__ float xs[16 * 1024];
    const int r0 = blockIdx.y * 16;
    const int c0 = blockIdx.x * 64;
    for (int i = threadIdx.x; i < 4096; i += 256)
        ((float4*)xs)[i] = ((const float4*)(hid + (size_t)r0 * 1024))[i];
    __syncthreads();
    const int col = c0 + (threadIdx.x & 63);
    const int rg = (threadIdx.x >> 6) * 4;
    float acc[4] = {0.f, 0.f, 0.f, 0.f};
    const float4* w4 = (const float4*)(W + (size_t)col * 1024);
    for (int k4 = 0; k4 < 256; ++k4) {
        float4 w = w4[k4];
#pragma unroll
        for (int rr = 0; rr < 4; ++rr) {
            float4 x = *(const float4*)&xs[(rg + rr) * 1024 + k4 * 4];
            acc[rr] += w.x * x.x + w.y * x.y + w.z * x.z + w.w * x.w;
        }
    }
    const float bb = bias[col];
#pragma unroll
    for (int rr = 0; rr < 4; ++rr) {
        const int row = r0 + rg + rr;
        tex[(size_t)row * 512 + col] = acc[rr] + bb + xga[(size_t)row * 512 + col];
    }
}

__global__ __launch_bounds__(256)
void norm_out(const float* __restrict__ tex, float* __restrict__ out)
{
    __shared__ float red[256];
    const int b = blockIdx.x;
    const int t = threadIdx.x;
    const float a = tex[b * 512 + t];
    const float c = tex[b * 512 + 256 + t];
    red[t] = a * a + c * c;
    __syncthreads();
    for (int s = 128; s > 0; s >>= 1) {
        if (t < s) red[t] += red[t + s];
        __syncthreads();
    }
    const float inv = 1.f / (sqrtf(red[0]) + 1e-8f);
    out[b * 512 + t] = a * inv;
    out[b * 512 + 256 + t] = c * inv;
}

extern "C" void kernel_launch(void* const* d_in, const int* in_sizes, int n_in,
                              void* d_out, int out_size, void* d_ws, size_t ws_size,
                              hipStream_t stream)
{
    const float* cap = (const float*)d_in[0];
    const int* lengths = (const int*)d_in[1];
    const float* Wq  = (const float*)d_in[2];
    const float* Wk  = (const float*)d_in[3];
    const float* Wv  = (const float*)d_in[4];
    const float* bq  = (const float*)d_in[5];
    const float* bk  = (const float*)d_in[6];
    const float* bv  = (const float*)d_in[7];
    const float* Wfq = (const float*)d_in[8];
    const float* bfq = (const float*)d_in[9];
    const float* Wfk = (const float*)d_in[10];
    const float* bfk = (const float*)d_in[11];
    const float* Wfg = (const float*)d_in[12];
    const float* bfg = (const float*)d_in[13];
    const float* g1  = (const float*)d_in[14];
    const float* b1  = (const float*)d_in[15];
    const float* m1  = (const float*)d_in[16];
    const float* v1  = (const float*)d_in[17];
    const float* Wm1 = (const float*)d_in[30];
    const float* bm1 = (const float*)d_in[31];
    const float* Wm2 = (const float*)d_in[32];
    const float* bm2 = (const float*)d_in[33];
    float* out = (float*)d_out;

    char* w = (char*)d_ws;
    const size_t MB = 1024 * 1024;
    short* capB = (short*)(w);                 // 32MB bf16 cap (valid throughout)
    short* Gbuf = (short*)(w + 32 * MB);       // 32MB [32768,512] bf16
    char* wp = w + 64 * MB;
    short* WkB   = (short*)wp; wp += 524288;   // [512,512] (kg's B)
    short* WaB   = (short*)wp; wp += 524288;   // composed Wfq@Wq_h
    short* WbB   = (short*)wp; wp += 524288;   // composed Wfk@Wk_h
    short* Wfg2B = (short*)wp; wp += 131072;
    float* ba     = (float*)wp; wp += 2048;
    float* bb     = (float*)wp; wp += 2048;
    float* qg     = (float*)wp; wp += 262144;
    float* scorep = (float*)wp; wp += 524288;   // [128][2][256][2]
    float* pbar   = (float*)wp; wp += 524288;
    float* xga    = (float*)wp; wp += 262144;
    float* hid    = (float*)wp; wp += 524288;
    float* tex    = (float*)wp; wp += 262144;

    // 1. bf16 casts: cap, Wk, Wfg2
    CastArgs ca;
    ca.src[0] = cap;          ca.dst[0] = capB;  ca.n4[0] = 4194304;
    ca.src[1] = Wk;           ca.dst[1] = WkB;   ca.n4[1] = 65536;
    ca.src[2] = Wfg + 65536;  ca.dst[2] = Wfg2B; ca.n4[2] = 16384;
    cast_multi<<<dim3(4096, 3), 256, 0, stream>>>(ca);

    // 2. composed Wa/ba and Wb/bb
    compose2<<<dim3(512, 2), 256, 0, stream>>>(Wq, bq, Wfq, bfq, Wk, bk, Wfk, bfk,
                                               WaB, ba, WbB, bb);

    // 3. G = (cap@Wb^T+bb)*(cap@Wa^T+ba)  (dual-B) -> Gbuf
    gemm_g<<<dim3(2, 256, 2), 256, 0, stream>>>(capB, WaB, WbB, ba, bb, Gbuf);

    // 4. qg at gathered rows (Q fp32 from cap)
    qg_kernel<<<dim3(256), 256, 0, stream>>>(cap, Gbuf, Wq, bq, Wfg, bfg, lengths, qg);

    // 5. kg gemm (interleaved dual kloop) + in-kernel K (fp32) + fused scores
    gemm_kg<<<dim3(2, 256, 2), 256, 0, stream>>>(Gbuf, Wfg2B, bfg + 256,
                                                 capB, WkB, bk, qg, scorep);

    // 6-7. softmax+pbar (bf16 cap), BN/residual
    pbar_kernel<<<dim3(8, 128), 256, 0, stream>>>(scorep, capB, pbar);
    bnx_kernel<<<dim3(128), 256, 0, stream>>>(pbar, cap, lengths, Wv, bv, g1, b1, m1, v1, xga);

    // 8-10. MLP, norm
    mlp1<<<dim3(16, 8), 256, 0, stream>>>(xga, Wm1, bm1, hid);
    mlp2<<<dim3(8, 8), 256, 0, stream>>>(hid, Wm2, bm2, xga, tex);
    norm_out<<<dim3(128), 256, 0, stream>>>(tex, out);
}